// Round 4
// baseline (308.663 us; speedup 1.0000x reference)
//
#include <hip/hip_runtime.h>
#include <cstdint>
#include <cstddef>

// ---------------- workspace layout (bytes) ----------------
// Wp   : packed gate-interleaved weight, bf16, 768x1024 (8 cb x 32 kb tiles, 96x32) = 1,572,864
// Fp   : packed fco_w, bf16, 256x256 (2 nb x 8 kb tiles, 128x32)                    =   131,072
// bp   : permuted bias (c = h*3+g), f32, 768
// hvp  : packed hidden vector, bf16, 32768x256 (256 mb x 8 kb tiles, 128x32)
#define WS_WP   0
#define WS_FCO  1572864
#define WS_BP   1703936
#define WS_HVP  1707008

typedef __attribute__((ext_vector_type(8))) __bf16 bf16x8;
typedef __attribute__((ext_vector_type(4))) float floatx4;

__device__ __forceinline__ unsigned short f2bf(float f) {
  unsigned int u = __builtin_bit_cast(unsigned int, f);
  u += 0x7fffu + ((u >> 16) & 1u);   // RNE
  return (unsigned short)(u >> 16);
}

__device__ __forceinline__ float sigmf(float z) {
  return __builtin_amdgcn_rcpf(1.f + __expf(-z));
}
__device__ __forceinline__ float tanh_(float z) {
  return 1.f - 2.f * __builtin_amdgcn_rcpf(1.f + __expf(2.f * z));
}

__device__ __forceinline__ void gld16(const void* g, void* l) {
  __builtin_amdgcn_global_load_lds(
      (const __attribute__((address_space(1))) unsigned int*)g,
      (__attribute__((address_space(3))) unsigned int*)l, 16, 0, 0);
}

// ---------------- merged pack kernel ----------------
// blocks 0..383: quaternion weight pack. Lane = h (coalesced reads, wave-uniform
// component/sign). c = h*3 + g', tiles (cb=c/96, kb=f/32) of 96x32, slot
// idx16 = nl*4 + (q ^ ((nl>>1)&3)).
// blocks 384..415: fco_w pack. Lane = n (coalesced reads), 128x32 tiles.
__global__ __launch_bounds__(256) void pack_k(
    const float* __restrict__ wr, const float* __restrict__ wi,
    const float* __restrict__ wj, const float* __restrict__ wk,
    const float* __restrict__ bx, const float* __restrict__ fw,
    unsigned short* __restrict__ Wp, unsigned short* __restrict__ Fp,
    float* __restrict__ bp) {
  int t = threadIdx.x;
  if (blockIdx.x < 384) {
    int gpp = blockIdx.x >> 7;        // 0..2 -> gates {input,output,cell}
    int oct = blockIdx.x & 127;       // f-octet
    int gp = gpp + 1;                 // index into wx_*[4,...] (skip dead forget gate)
    int h = t;                        // 0..255, lane-contiguous
    int hb = h >> 6, hr = h & 63;     // hb wave-uniform
    int f0 = oct << 3;
    int fb = f0 >> 8, fr0 = f0 & 255;
    const int   comp_t[4][4] = {{0,1,2,3},{1,0,3,2},{2,3,0,1},{3,2,1,0}};
    const float sign_t[4][4] = {{1.f,-1.f,-1.f,-1.f},{1.f,1.f,-1.f,1.f},
                                {1.f,1.f,1.f,-1.f},{1.f,-1.f,1.f,1.f}};
    const float* srcs[4] = {wr, wi, wj, wk};
    const float* s = srcs[comp_t[hb][fb]] + ((size_t)((gp << 8) + fr0)) * 64 + hr;
    float sg = sign_t[hb][fb];
    unsigned short v[8];
#pragma unroll
    for (int j = 0; j < 8; ++j) v[j] = f2bf(sg * s[(size_t)j * 64]);  // coalesced
    int c = h * 3 + gpp;
    int cb = c / 96, nl = c % 96;
    int kb = oct >> 2, q = oct & 3;
    int idx16 = (nl << 2) + (q ^ ((nl >> 1) & 3));
    uint4 val = make_uint4(
        (unsigned)v[0] | ((unsigned)v[1] << 16), (unsigned)v[2] | ((unsigned)v[3] << 16),
        (unsigned)v[4] | ((unsigned)v[5] << 16), (unsigned)v[6] | ((unsigned)v[7] << 16));
    *(uint4*)(Wp + (size_t)(cb * 32 + kb) * 3072 + idx16 * 8) = val;
    if (oct == 0) bp[c] = bx[(gp << 8) + h];
  } else {
    int oct = blockIdx.x - 384;       // k-octet 0..31
    int n = t;
    int k0 = oct << 3;
    unsigned short v[8];
#pragma unroll
    for (int j = 0; j < 8; ++j) v[j] = f2bf(fw[(size_t)(k0 + j) * 256 + n]);  // coalesced
    int nb = n >> 7, nl = n & 127, kb = oct >> 2, q = oct & 3;
    int idx16 = (nl << 2) + (q ^ ((nl >> 1) & 3));
    uint4 val = make_uint4(
        (unsigned)v[0] | ((unsigned)v[1] << 16), (unsigned)v[2] | ((unsigned)v[3] << 16),
        (unsigned)v[4] | ((unsigned)v[5] << 16), (unsigned)v[6] | ((unsigned)v[7] << 16));
    *(uint4*)(Fp + (size_t)((nb << 3) + kb) * 4096 + idx16 * 8) = val;
  }
}

// ---------------- GEMM1 + fused LSTM gates ----------------
// Tile 128x96, 4 waves of 64x48, BK=32, acc[4][3] (48 acc VGPR -> 4 waves/SIMD).
// A fp32 via global_load_lds with XOR-quad swizzle; cvt to bf16 after ds_read.
// B from pre-swizzled Wp. Epilogue: 4 passes of 32 rows, LDS 22.5 KB total.
__global__ __launch_bounds__(256, 4) void gemm1_k(
    const float* __restrict__ x, const unsigned short* __restrict__ Wp,
    const float* __restrict__ bp, unsigned short* __restrict__ hvp) {
  __shared__ char smem[22528];                 // A fp32 16K + B bf16 6K; epi 32x100 f32
  float* sAf = (float*)smem;
  unsigned short* sBs = (unsigned short*)(smem + 16384);
  float* zep = (float*)smem;

  const int t = threadIdx.x;
  const int lane = t & 63, wid = t >> 6;
  const int wm = wid >> 1, wn = wid & 1;
  const int lrow = lane & 15, q = lane >> 4;
  const int row0 = blockIdx.x * 128;
  const int cby = blockIdx.y;                  // 0..7, 96 interleaved cols (32 h)
  const float* xbase = x + (size_t)row0 * 1024;

  floatx4 acc[4][3];
#pragma unroll
  for (int i = 0; i < 4; ++i)
#pragma unroll
    for (int j = 0; j < 3; ++j) acc[i][j] = (floatx4){0.f, 0.f, 0.f, 0.f};

  for (int kt = 0; kt < 32; ++kt) {
    const int k0 = kt * 32;
    // A: 1024 fp32-quad slots; global address carries the swizzle
#pragma unroll
    for (int i = 0; i < 4; ++i) {
      int s = t + i * 256;
      int m = s >> 3, j = s & 7, jj = j ^ (m & 7);
      gld16(xbase + (size_t)m * 1024 + k0 + jj * 4, sAf + s * 4);
    }
    // B: 384 slots, packed order == LDS order
    const unsigned short* bt = Wp + (size_t)(cby * 32 + kt) * 3072;
    gld16(bt + t * 8, sBs + t * 8);
    if (t < 128) gld16(bt + 2048 + t * 8, sBs + 2048 + t * 8);
    __syncthreads();
    bf16x8 af[4], bf[3];
#pragma unroll
    for (int mt = 0; mt < 4; ++mt) {
      int m = wm * 64 + mt * 16 + lrow;
      const float4 a0 = *(const float4*)(sAf + (m * 8 + ((2 * q) ^ (m & 7))) * 4);
      const float4 a1 = *(const float4*)(sAf + (m * 8 + ((2 * q + 1) ^ (m & 7))) * 4);
      bf16x8 v;
      v[0] = (__bf16)a0.x; v[1] = (__bf16)a0.y; v[2] = (__bf16)a0.z; v[3] = (__bf16)a0.w;
      v[4] = (__bf16)a1.x; v[5] = (__bf16)a1.y; v[6] = (__bf16)a1.z; v[7] = (__bf16)a1.w;
      af[mt] = v;
    }
#pragma unroll
    for (int nt = 0; nt < 3; ++nt) {
      int n = wn * 48 + nt * 16 + lrow;
      int off16 = (n << 2) + (q ^ ((n >> 1) & 3));
      bf[nt] = *(const bf16x8*)(const void*)(sBs + off16 * 8);
    }
#pragma unroll
    for (int mt = 0; mt < 4; ++mt)
#pragma unroll
      for (int nt = 0; nt < 3; ++nt)
        acc[mt][nt] = __builtin_amdgcn_mfma_f32_16x16x32_bf16(af[mt], bf[nt], acc[mt][nt], 0, 0, 0);
    __syncthreads();
  }

  // Epilogue: 4 passes of 32 rows; fused gates; hv stored in gemm2's packed layout.
  const float* bp0 = bp + cby * 96;
  const int row_ip = t >> 3, ho = t & 7;
  unsigned short* hvt = hvp + (size_t)(blockIdx.x * 8 + cby) * 4096;
#pragma unroll
  for (int p = 0; p < 4; ++p) {
    if (wm == (p >> 1)) {
#pragma unroll
      for (int mt2 = 0; mt2 < 2; ++mt2) {
        int mt = (p & 1) * 2 + mt2;
#pragma unroll
        for (int nt = 0; nt < 3; ++nt)
#pragma unroll
          for (int r = 0; r < 4; ++r)
            zep[(mt2 * 16 + q * 4 + r) * 100 + wn * 48 + nt * 16 + lrow] = acc[mt][nt][r];
      }
    }
    __syncthreads();
    unsigned short v[4];
#pragma unroll
    for (int j = 0; j < 4; ++j) {
      int hl = ho * 4 + j;                    // 0..31 local h
      float zi = zep[row_ip * 100 + hl * 3 + 0] + bp0[hl * 3 + 0];
      float zo = zep[row_ip * 100 + hl * 3 + 1] + bp0[hl * 3 + 1];
      float zc = zep[row_ip * 100 + hl * 3 + 2] + bp0[hl * 3 + 2];
      float it = sigmf(zi);
      float ot = sigmf(zo);
      float cc = it * tanh_(zc);
      v[j] = f2bf(ot * tanh_(cc));
    }
    int ml = p * 32 + row_ip;
    int qq = ho >> 1;
    int idx16 = (ml << 2) + (qq ^ ((ml >> 1) & 3));
    uint2 val = make_uint2((unsigned)v[0] | ((unsigned)v[1] << 16),
                           (unsigned)v[2] | ((unsigned)v[3] << 16));
    *(uint2*)(hvt + (size_t)idx16 * 8 + (ho & 1) * 4) = val;
    __syncthreads();
  }
}

// ---------------- GEMM2: out = hv @ fco_w + fco_b (fp32 output) ----------------
// B-half (256x128) resident in LDS (loaded once); A fragments direct global->VGPR
// from packed hvp (1KB-contiguous per instr). No barriers in the K-loop.
__global__ __launch_bounds__(256, 4) void gemm2_k(
    const unsigned short* __restrict__ hvp, const unsigned short* __restrict__ Fp,
    const float* __restrict__ fcob, float* __restrict__ out) {
  __shared__ unsigned short sB[32768];         // 64 KB: 8 k-tiles of 128x32
  const int t = threadIdx.x;
  const int lane = t & 63, wid = t >> 6;
  const int wm = wid >> 1, wn = wid & 1;
  const int lrow = lane & 15, q = lane >> 4;
  const int mb = blockIdx.x, nb = blockIdx.y;

  const unsigned short* fpb = Fp + (size_t)nb * 32768;
#pragma unroll
  for (int i = 0; i < 16; ++i) gld16(fpb + (t + i * 256) * 8, sB + (t + i * 256) * 8);

  floatx4 acc[4][4];
#pragma unroll
  for (int i = 0; i < 4; ++i)
#pragma unroll
    for (int j = 0; j < 4; ++j) acc[i][j] = (floatx4){0.f, 0.f, 0.f, 0.f};
  __syncthreads();

#pragma unroll
  for (int kt = 0; kt < 8; ++kt) {
    const unsigned short* at_ = hvp + (size_t)(mb * 8 + kt) * 4096;
    bf16x8 af[4], bf[4];
#pragma unroll
    for (int mt = 0; mt < 4; ++mt) {
      int m = wm * 64 + mt * 16 + lrow;
      int o = (m << 2) + (q ^ ((m >> 1) & 3));
      af[mt] = *(const bf16x8*)(const void*)(at_ + o * 8);    // global, coalesced
    }
#pragma unroll
    for (int nt = 0; nt < 4; ++nt) {
      int n = wn * 64 + nt * 16 + lrow;
      int o = (n << 2) + (q ^ ((n >> 1) & 3));
      bf[nt] = *(const bf16x8*)(const void*)(sB + kt * 4096 + o * 8);
    }
#pragma unroll
    for (int mt = 0; mt < 4; ++mt)
#pragma unroll
      for (int nt = 0; nt < 4; ++nt)
        acc[mt][nt] = __builtin_amdgcn_mfma_f32_16x16x32_bf16(af[mt], bf[nt], acc[mt][nt], 0, 0, 0);
  }
#pragma unroll
  for (int nt = 0; nt < 4; ++nt) {
    int colg = nb * 128 + wn * 64 + nt * 16 + lrow;
    float bias = fcob[colg];
#pragma unroll
    for (int mt = 0; mt < 4; ++mt) {
      int rowg = mb * 128 + wm * 64 + mt * 16 + q * 4;
#pragma unroll
      for (int r = 0; r < 4; ++r)
        out[(size_t)(rowg + r) * 256 + colg] = acc[mt][nt][r] + bias;
    }
  }
}

extern "C" void kernel_launch(void* const* d_in, const int* in_sizes, int n_in,
                              void* d_out, int out_size, void* d_ws, size_t ws_size,
                              hipStream_t stream) {
  const float* x  = (const float*)d_in[0];
  const float* wr = (const float*)d_in[1];
  const float* wi = (const float*)d_in[2];
  const float* wj = (const float*)d_in[3];
  const float* wk = (const float*)d_in[4];
  const float* bx = (const float*)d_in[5];
  // d_in[6..9] = uh_* are dead (h0 == 0)
  const float* fw = (const float*)d_in[10];
  const float* fb = (const float*)d_in[11];
  char* ws = (char*)d_ws;
  unsigned short* Wp  = (unsigned short*)(ws + WS_WP);
  unsigned short* Fp  = (unsigned short*)(ws + WS_FCO);
  float*          bp  = (float*)(ws + WS_BP);
  unsigned short* hvp = (unsigned short*)(ws + WS_HVP);
  float*          out = (float*)d_out;

  hipLaunchKernelGGL(pack_k,  dim3(416),    dim3(256), 0, stream, wr, wi, wj, wk, bx, fw, Wp, Fp, bp);
  hipLaunchKernelGGL(gemm1_k, dim3(256, 8), dim3(256), 0, stream, x, Wp, bp, hvp);
  hipLaunchKernelGGL(gemm2_k, dim3(256, 2), dim3(256), 0, stream, hvp, Fp, fb, out);
}